// Round 9
// baseline (1761.020 us; speedup 1.0000x reference)
//
#include <hip/hip_runtime.h>
#include <cstdint>
#include <cstddef>

typedef unsigned short ushort_t;
typedef unsigned int uint_t;
typedef unsigned long long u64_t;
typedef float v2f __attribute__((ext_vector_type(2)));

#define B_ 16
#define N_ 4096
#define S_ 1024
#define K_ 32
#define NR 524288    // B*S*K rows
#define NQ 16384     // B*S queries

__device__ __forceinline__ float bf2f(ushort_t u) {
    union { uint_t i; float f; } x; x.i = ((uint_t)u) << 16; return x.f;
}
__device__ __forceinline__ ushort_t f2bf(float f) {
    union { float f; uint_t u; } x; x.f = f;
    uint_t u = x.u;
    uint_t r = (u + 0x7fffu + ((u >> 16) & 1u)) >> 16;   // RNE
    return (ushort_t)r;
}

// ---------------------------------------------------------------------------
// DPP primitives. update_dpp(idt, v, ctrl, 0xF, 0xF, false): invalid lanes
// receive idt (identity).
// ---------------------------------------------------------------------------
template <int CTRL>
__device__ __forceinline__ uint_t dppmov(uint_t v, uint_t idt) {
    return (uint_t)__builtin_amdgcn_update_dpp((int)idt, (int)v, CTRL, 0xF, 0xF, false);
}
template <int CTRL>
__device__ __forceinline__ float dppsum(float v) {
    return v + __uint_as_float(dppmov<CTRL>(__float_as_uint(v), 0u));              // idt = +0.0
}
template <int CTRL>
__device__ __forceinline__ float dppmaxf(float v) {
    return fmaxf(v, __uint_as_float(dppmov<CTRL>(__float_as_uint(v), 0xFF800000u))); // idt = -inf
}

// wave-64 argmax/argmin over unique u64 keys; result in lane 63.
__device__ __forceinline__ void wave_argmax64(uint_t& hi, uint_t& lo) {
#define STEP_MAX(C) { uint_t nh = dppmov<C>(hi, 0u); uint_t nl = dppmov<C>(lo, 0u); \
    u64_t a = ((u64_t)hi << 32) | lo, bb = ((u64_t)nh << 32) | nl; \
    if (bb > a) { hi = nh; lo = nl; } }
    STEP_MAX(0x111) STEP_MAX(0x112) STEP_MAX(0x114) STEP_MAX(0x118)
    STEP_MAX(0x142) STEP_MAX(0x143)
#undef STEP_MAX
}
__device__ __forceinline__ void wave_argmin64(uint_t& hi, uint_t& lo) {
#define STEP_MIN(C) { uint_t nh = dppmov<C>(hi, 0xFFFFFFFFu); uint_t nl = dppmov<C>(lo, 0xFFFFFFFFu); \
    u64_t a = ((u64_t)hi << 32) | lo, bb = ((u64_t)nh << 32) | nl; \
    if (bb < a) { hi = nh; lo = nl; } }
    STEP_MIN(0x111) STEP_MIN(0x112) STEP_MIN(0x114) STEP_MIN(0x118)
    STEP_MIN(0x142) STEP_MIN(0x143)
#undef STEP_MIN
}

// ---------------------------------------------------------------------------
// prep: weights fp32 -> fp32 transposed. wt0[c][64], wt1[c][64], wt2[c][128]
// ---------------------------------------------------------------------------
__global__ __launch_bounds__(256) void prep_kernel(
        const float* __restrict__ W0, const float* __restrict__ W1,
        const float* __restrict__ W2,
        float* __restrict__ wt0, float* __restrict__ wt1, float* __restrict__ wt2) {
    int tid = threadIdx.x;
    for (int i = tid; i < 64 * 67; i += 256) { int o = i / 67, c = i % 67; wt0[c * 64 + o] = W0[i]; }
    for (int i = tid; i < 64 * 64; i += 256) { int o = i >> 6, c = i & 63; wt1[c * 64 + o] = W1[i]; }
    for (int i = tid; i < 128 * 64; i += 256) { int o = i >> 6, c = i & 63; wt2[c * 128 + o] = W2[i]; }
}

// ---------------------------------------------------------------------------
// FPS: one block (4 waves) per batch, 16 pts/thread packed as float2 pairs.
// NO global stores in the loop (farh history in LDS; coalesced epilogue) so
// the compiler's pre-barrier waitcnt drains LDS only, never vmcnt.
// u64-key tree + DPP wave argmax + one barrier combine. Key=(dist_bits,~p).
// ---------------------------------------------------------------------------
__global__ __launch_bounds__(256) void fps_kernel(
        const float* __restrict__ xyz, float* __restrict__ out_sxyz) {
    #pragma clang fp contract(off)
    __shared__ float4 pts[N_];
    __shared__ uint2 cand[2][4];
    __shared__ int farh[S_];
    int b = blockIdx.x, tid = threadIdx.x;
    int wv = tid >> 6, lane = tid & 63;
    const float* base = xyz + (size_t)b * N_ * 3;

    v2f px[8], py[8], pz[8], dist[8];
    #pragma unroll
    for (int t = 0; t < 16; t++) {
        int p = tid + t * 256;
        float x = base[p * 3 + 0];
        float y = base[p * 3 + 1];
        float z = base[p * 3 + 2];
        px[t >> 1][t & 1] = x; py[t >> 1][t & 1] = y; pz[t >> 1][t & 1] = z;
        pts[p] = make_float4(x, y, z, 0.0f);
        dist[t >> 1][t & 1] = 1e10f;
    }
    __syncthreads();

    int far = 0;
    for (int i = 0; i < S_; i++) {
        float4 c = pts[far];                       // ds_read_b128
        if (tid == 0) farh[i] = far;
        v2f cx = { c.x, c.x }, cy = { c.y, c.y }, cz = { c.z, c.z };
        #pragma unroll
        for (int j = 0; j < 8; j++) {
            v2f dx = px[j] - cx, dy = py[j] - cy, dz = pz[j] - cz;
            v2f d = (dx * dx + dy * dy) + dz * dz;   // ref sum order
            dist[j] = __builtin_elementwise_min(dist[j], d);
        }
        // local tree argmax over 16 candidates via u64 keys (exact total order)
        uint_t kh[16], kl[16];
        #pragma unroll
        for (int t = 0; t < 16; t++) {
            kh[t] = __float_as_uint(dist[t >> 1][t & 1]);  // dist>=0: uint order = float order
            kl[t] = ~(uint_t)(tid + t * 256);
        }
        #pragma unroll
        for (int st = 8; st >= 1; st >>= 1) {
            #pragma unroll
            for (int t = 0; t < 8; t++) {
                if (t < st) {
                    u64_t a = ((u64_t)kh[t] << 32) | kl[t];
                    u64_t bb = ((u64_t)kh[t + st] << 32) | kl[t + st];
                    if (bb > a) { kh[t] = kh[t + st]; kl[t] = kl[t + st]; }
                }
            }
        }
        uint_t bh = kh[0], bl = kl[0];
        wave_argmax64(bh, bl);                     // lane 63 has wave winner
        int buf = i & 1;
        if (lane == 63) cand[buf][wv] = make_uint2(bh, bl);
        __syncthreads();
        uint2 c0 = cand[buf][0], c1 = cand[buf][1], c2 = cand[buf][2], c3 = cand[buf][3];
        u64_t best = ((u64_t)c0.x << 32) | c0.y;
        u64_t k1 = ((u64_t)c1.x << 32) | c1.y; if (k1 > best) best = k1;
        u64_t k2 = ((u64_t)c2.x << 32) | c2.y; if (k2 > best) best = k2;
        u64_t k3 = ((u64_t)c3.x << 32) | c3.y; if (k3 > best) best = k3;
        far = (int)((~(uint_t)best) & 4095u);
    }
    __syncthreads();
    // epilogue: coalesced centroid writes (output 0 doubles as knn's qxyz)
    for (int i = tid; i < S_; i += 256) {
        float4 c = pts[farh[i]];
        int qi = b * S_ + i;
        out_sxyz[qi * 3 + 0] = c.x;
        out_sxyz[qi * 3 + 1] = c.y;
        out_sxyz[qi * 3 + 2] = c.z;
    }
}

// ---------------------------------------------------------------------------
// KNN: one wave per query -> 32 neighbor indices (unchanged from R8).
// ---------------------------------------------------------------------------
__global__ __launch_bounds__(64) void knn_kernel(
        const float* __restrict__ xyz, const float* __restrict__ qxyz,
        int* __restrict__ nbr) {
    #pragma clang fp contract(off)
    __shared__ uint_t dsm[N_];
    int bs = blockIdx.x;
    int b = bs >> 10;
    int lane = threadIdx.x;
    const float* xb = xyz + (size_t)b * N_ * 3;

    float qx = qxyz[bs * 3 + 0], qy = qxyz[bs * 3 + 1], qz = qxyz[bs * 3 + 2];
    float qq = (qx * qx + qy * qy) + qz * qz;

    uint_t ulv = 0xFFFFFFFFu; int li = 0;
    for (int s = 0; s < 64; s++) {
        int p = s * 64 + lane;
        float x = xb[p * 3 + 0];
        float y = xb[p * 3 + 1];
        float z = xb[p * 3 + 2];
        float pp = (x * x + y * y) + z * z;
        float dt = (qx * x + qy * y) + qz * z;
        float d = (qq + pp) - 2.0f * dt;               // matches ref
        uint_t ub = __float_as_uint(d);
        ub ^= (uint_t)(((int)ub >> 31)) | 0x80000000u; // sortable transform
        dsm[s * 64 + ((lane + s) & 63)] = ub;          // swizzled store
        if (ub < ulv) { ulv = ub; li = p; }
    }
    __syncthreads();

    u64_t mask = 0ull;
    int my_nbr = 0;
    for (int r = 0; r < K_; r++) {
        uint_t hh = ulv, ll = (uint_t)li;
        wave_argmin64(hh, ll);
        int idx = (int)(uint_t)__builtin_amdgcn_readlane((int)ll, 63);
        int glane = idx & 63, srow = idx >> 6;
        if (lane == r) my_nbr = idx;
        if (lane == glane) mask |= 1ull << srow;
        uint_t gml = (uint_t)__builtin_amdgcn_readlane((int)(uint_t)mask, glane);
        uint_t gmh = (uint_t)__builtin_amdgcn_readlane((int)(uint_t)(mask >> 32), glane);
        u64_t gm = ((u64_t)gmh << 32) | gml;
        uint_t cv = ((gm >> lane) & 1ull) ? 0xFFFFFFFFu
                                          : dsm[lane * 64 + ((glane + lane) & 63)];
        uint_t ci = (uint_t)(lane * 64 + glane);
        wave_argmin64(cv, ci);
        uint_t rv = (uint_t)__builtin_amdgcn_readlane((int)cv, 63);
        uint_t ri = (uint_t)__builtin_amdgcn_readlane((int)ci, 63);
        if (lane == glane) { ulv = rv; li = (int)ri; }
    }
    if (lane < K_) nbr[bs * K_ + lane] = my_nbr;
}

// ---------------------------------------------------------------------------
// L0: one thread per row. float4 gather + 67x64 FMA -> yT bf16. Fused BN
// stats: per-wave DPP sums -> block partials MPart[bx*128 + (s:0-63|q:64-127)].
// ---------------------------------------------------------------------------
__global__ __launch_bounds__(256) void l0_kernel(
        const float* __restrict__ xyz, const float* __restrict__ fea,
        const float* __restrict__ qxyz, const int* __restrict__ nbr,
        const float* __restrict__ wt0, ushort_t* __restrict__ yT,
        float* __restrict__ MPart) {
    int bx = blockIdx.x, tid = threadIdx.x;
    int row = bx * 256 + tid;
    int lane = tid & 63, wv = tid >> 6;
    int bs = row >> 5, b = bs >> 10;
    int p = nbr[row];
    p = (p < 0) ? 0 : (p > N_ - 1 ? N_ - 1 : p);
    float qx = qxyz[bs * 3 + 0], qy = qxyz[bs * 3 + 1], qz = qxyz[bs * 3 + 2];
    const float* xb = xyz + ((size_t)b * N_ + p) * 3;
    float dx = xb[0] - qx, dy = xb[1] - qy, dz = xb[2] - qz;

    float acc[64];
    #pragma unroll
    for (int o = 0; o < 64; o++)
        acc[o] = fmaf(dz, wt0[128 + o], fmaf(dy, wt0[64 + o], dx * wt0[o]));

    const float4* fr = (const float4*)(fea + ((size_t)b * N_ + p) * 64);
    #pragma unroll 2
    for (int i = 0; i < 16; i++) {
        float4 u = fr[i];
        float ua[4] = { u.x, u.y, u.z, u.w };
        #pragma unroll
        for (int j = 0; j < 4; j++) {
            const float* w = wt0 + (3 + i * 4 + j) * 64;
            #pragma unroll
            for (int o = 0; o < 64; o++) acc[o] = fmaf(ua[j], w[o], acc[o]);
        }
    }
    __shared__ float Ssm[4][64], Qsm[4][64];
    #pragma unroll 4
    for (int o = 0; o < 64; o++) {
        ushort_t hb = f2bf(acc[o]);
        yT[(size_t)o * NR + row] = hb;
        float v = bf2f(hb);                        // stats on stored values
        float s = v, q = v * v;
        s = dppsum<0x111>(s); s = dppsum<0x112>(s); s = dppsum<0x114>(s);
        s = dppsum<0x118>(s); s = dppsum<0x142>(s); s = dppsum<0x143>(s);
        q = dppsum<0x111>(q); q = dppsum<0x112>(q); q = dppsum<0x114>(q);
        q = dppsum<0x118>(q); q = dppsum<0x142>(q); q = dppsum<0x143>(q);
        if (lane == 63) { Ssm[wv][o] = s; Qsm[wv][o] = q; }
    }
    __syncthreads();
    if (tid < 64)
        MPart[bx * 128 + tid] = Ssm[0][tid] + Ssm[1][tid] + Ssm[2][tid] + Ssm[3][tid];
    else if (tid < 128) {
        int ch = tid - 64;
        MPart[bx * 128 + tid] = Qsm[0][ch] + Qsm[1][ch] + Qsm[2][ch] + Qsm[3][ch];
    }
}

// ---------------------------------------------------------------------------
// stats_fin: reduce 2048 block partials per channel -> ab (a, c).
// ---------------------------------------------------------------------------
__global__ __launch_bounds__(256) void stats_fin(
        const float* __restrict__ MPart, const float* __restrict__ g,
        const float* __restrict__ be, float* __restrict__ ab) {
    int o = blockIdx.x;   // 0..63
    float s = 0.0f, q = 0.0f;
    for (int col = threadIdx.x; col < 2048; col += 256) {
        s += MPart[col * 128 + o];
        q += MPart[col * 128 + 64 + o];
    }
    __shared__ float ls[256], lq[256];
    int tid = threadIdx.x;
    ls[tid] = s; lq[tid] = q;
    __syncthreads();
    for (int off = 128; off >= 1; off >>= 1) {
        if (tid < off) { ls[tid] += ls[tid + off]; lq[tid] += lq[tid + off]; }
        __syncthreads();
    }
    if (tid == 0) {
        double mu = (double)ls[0] / (double)NR;
        double var = (double)lq[0] / (double)NR - mu * mu;
        if (var < 0.0) var = 0.0;
        double a = (double)g[o] / sqrt(var + 1e-5);
        ab[o]      = (float)a;
        ab[64 + o] = (float)((double)be[o] - mu * a);
    }
}

// ---------------------------------------------------------------------------
// L1: in-place on yT + fused BN stats (same scheme as l0).
// ---------------------------------------------------------------------------
__global__ __launch_bounds__(256) void l1_kernel(
        ushort_t* yT, const float* __restrict__ wt1, const float* __restrict__ ab,
        float* __restrict__ MPart) {
    int bx = blockIdx.x, tid = threadIdx.x;
    int row = bx * 256 + tid;
    int lane = tid & 63, wv = tid >> 6;
    float xv[64];
    #pragma unroll
    for (int c = 0; c < 64; c++)
        xv[c] = fmaxf(fmaf(bf2f(yT[(size_t)c * NR + row]), ab[c], ab[64 + c]), 0.0f);
    float acc[64];
    #pragma unroll
    for (int o = 0; o < 64; o++) acc[o] = 0.0f;
    #pragma unroll 4
    for (int c = 0; c < 64; c++) {
        const float* w = wt1 + c * 64;
        #pragma unroll
        for (int o = 0; o < 64; o++) acc[o] = fmaf(xv[c], w[o], acc[o]);
    }
    __shared__ float Ssm[4][64], Qsm[4][64];
    #pragma unroll 4
    for (int o = 0; o < 64; o++) {
        ushort_t hb = f2bf(acc[o]);
        yT[(size_t)o * NR + row] = hb;
        float v = bf2f(hb);
        float s = v, q = v * v;
        s = dppsum<0x111>(s); s = dppsum<0x112>(s); s = dppsum<0x114>(s);
        s = dppsum<0x118>(s); s = dppsum<0x142>(s); s = dppsum<0x143>(s);
        q = dppsum<0x111>(q); q = dppsum<0x112>(q); q = dppsum<0x114>(q);
        q = dppsum<0x118>(q); q = dppsum<0x142>(q); q = dppsum<0x143>(q);
        if (lane == 63) { Ssm[wv][o] = s; Qsm[wv][o] = q; }
    }
    __syncthreads();
    if (tid < 64)
        MPart[bx * 128 + tid] = Ssm[0][tid] + Ssm[1][tid] + Ssm[2][tid] + Ssm[3][tid];
    else if (tid < 128) {
        int ch = tid - 64;
        MPart[bx * 128 + tid] = Qsm[0][ch] + Qsm[1][ch] + Qsm[2][ch] + Qsm[3][ch];
    }
}

// ---------------------------------------------------------------------------
// L2 stats + EARLY MAXPOOL (DPP reductions): recompute y2 rows, per-channel
// sums (s,q) -> block partials, per-query max M (BN2 scale a>0: maxpool
// commutes with BN+ReLU). part2s: [2][128][2048]. M: [16384][128].
// ---------------------------------------------------------------------------
__global__ __launch_bounds__(256) void l2s_kernel(
        const ushort_t* __restrict__ yT, const float* __restrict__ wt2,
        const float* __restrict__ ab1, float* __restrict__ part2s,
        float* __restrict__ M) {
    int bx = blockIdx.x, half = blockIdx.y;
    int tid = threadIdx.x;
    int row = bx * 256 + tid;
    int lane = tid & 63, wv = tid >> 6;
    float xv[64];
    #pragma unroll
    for (int c = 0; c < 64; c++)
        xv[c] = fmaxf(fmaf(bf2f(yT[(size_t)c * NR + row]), ab1[c], ab1[64 + c]), 0.0f);
    float acc[64];
    #pragma unroll
    for (int o = 0; o < 64; o++) acc[o] = 0.0f;
    const float* w = wt2 + half * 64;
    #pragma unroll 4
    for (int c = 0; c < 64; c++) {
        const float* wr = w + c * 128;
        #pragma unroll
        for (int o = 0; o < 64; o++) acc[o] = fmaf(xv[c], wr[o], acc[o]);
    }
    __shared__ float Msm[4][2][64];
    __shared__ float Ssm[4][64], Qsm[4][64];
    #pragma unroll 4
    for (int o = 0; o < 64; o++) {
        float v = acc[o];
        float m = v;
        m = dppmaxf<0x111>(m); m = dppmaxf<0x112>(m); m = dppmaxf<0x114>(m);
        m = dppmaxf<0x118>(m); m = dppmaxf<0x142>(m);   // lane31: max(0..31), lane63: max(32..63)
        float s = v, q = v * v;
        s = dppsum<0x111>(s); s = dppsum<0x112>(s); s = dppsum<0x114>(s);
        s = dppsum<0x118>(s); s = dppsum<0x142>(s); s = dppsum<0x143>(s);
        q = dppsum<0x111>(q); q = dppsum<0x112>(q); q = dppsum<0x114>(q);
        q = dppsum<0x118>(q); q = dppsum<0x142>(q); q = dppsum<0x143>(q);
        if (lane == 31) Msm[wv][0][o] = m;
        if (lane == 63) { Msm[wv][1][o] = m; Ssm[wv][o] = s; Qsm[wv][o] = q; }
    }
    __syncthreads();
    // M epilogue: 512 entries, coalesced
    #pragma unroll
    for (int r = 0; r < 2; r++) {
        int e = tid + r * 256;
        int ewv = e >> 7, eq = (e >> 6) & 1, eo = e & 63;
        M[(size_t)(bx * 8 + ewv * 2 + eq) * 128 + half * 64 + eo] = Msm[ewv][eq][eo];
    }
    if (tid < 64) {
        float s = Ssm[0][tid] + Ssm[1][tid] + Ssm[2][tid] + Ssm[3][tid];
        part2s[(size_t)(half * 64 + tid) * 2048 + bx] = s;
    } else if (tid < 128) {
        int ch = tid - 64;
        float q = Qsm[0][ch] + Qsm[1][ch] + Qsm[2][ch] + Qsm[3][ch];
        part2s[(size_t)128 * 2048 + (size_t)(half * 64 + ch) * 2048 + bx] = q;
    }
}

__global__ __launch_bounds__(256) void stats2_fin(
        const float* __restrict__ part2s, const float* __restrict__ g,
        const float* __restrict__ be, float* __restrict__ ab2) {
    int og = blockIdx.x;  // 0..127
    float s = 0.0f, q = 0.0f;
    for (int col = threadIdx.x; col < 2048; col += 256) {
        s += part2s[(size_t)og * 2048 + col];
        q += part2s[(size_t)128 * 2048 + (size_t)og * 2048 + col];
    }
    __shared__ float ls[256], lq[256];
    int tid = threadIdx.x;
    ls[tid] = s; lq[tid] = q;
    __syncthreads();
    for (int off = 128; off >= 1; off >>= 1) {
        if (tid < off) { ls[tid] += ls[tid + off]; lq[tid] += lq[tid + off]; }
        __syncthreads();
    }
    if (tid == 0) {
        double mu = (double)ls[0] / (double)NR;
        double var = (double)lq[0] / (double)NR - mu * mu;
        if (var < 0.0) var = 0.0;
        double a = (double)g[og] / sqrt(var + 1e-5);
        ab2[og]       = (float)a;
        ab2[128 + og] = (float)((double)be[og] - mu * a);
    }
}

// ---------------------------------------------------------------------------
// fin: out = relu(a*M + c)  (valid: a = g/sqrt(var) > 0).
// ---------------------------------------------------------------------------
__global__ __launch_bounds__(256) void fin_kernel(
        const float* __restrict__ M, const float* __restrict__ ab2,
        float* __restrict__ out) {
    int idx = blockIdx.x * 256 + threadIdx.x;   // 0 .. 2097151
    int og = idx & 127;
    out[49152 + idx] = fmaxf(fmaf(M[idx], ab2[og], ab2[128 + og]), 0.0f);
}

// ---------------------------------------------------------------------------
extern "C" void kernel_launch(void* const* d_in, const int* in_sizes, int n_in,
                              void* d_out, int out_size, void* d_ws, size_t ws_size,
                              hipStream_t stream) {
    const float* xyz = (const float*)d_in[0];
    const float* fea = (const float*)d_in[1];
    const float* W0  = (const float*)d_in[2];
    const float* g0  = (const float*)d_in[4];
    const float* be0 = (const float*)d_in[5];
    const float* W1  = (const float*)d_in[6];
    const float* g1  = (const float*)d_in[8];
    const float* be1 = (const float*)d_in[9];
    const float* W2  = (const float*)d_in[10];
    const float* g2  = (const float*)d_in[12];
    const float* be2 = (const float*)d_in[13];
    float* out = (float*)d_out;

    char* w = (char*)d_ws;
    // footprint ~74.1 MB (proven layout)
    ushort_t* yT    = (ushort_t*)(w);                      // 67,108,864
    int*      nbr   = (int*)     (w + 67108864);           //  2,097,152 (dead after l0)
    float*    part2s= (float*)   (w + 67108864);           //  2,097,152 (l2s partials, aliases nbr)
    float*    M     = (float*)   (w + 69222400);           //  8,388,608
    float*    MPart = (float*)   (w + 69222400);           //  1,048,576 (aliases M; dead before l2s)
    float*    ab0   = (float*)   (w + 77611008);           //        512
    float*    ab1   = (float*)   (w + 77611520);           //        512
    float*    ab2   = (float*)   (w + 77612032);           //      1,024
    float*    wt0   = (float*)   (w + 77613056);           //     17,152
    float*    wt1   = (float*)   (w + 77630208);           //     16,384
    float*    wt2   = (float*)   (w + 77646592);           //     32,768

    prep_kernel<<<1, 256, 0, stream>>>(W0, W1, W2, wt0, wt1, wt2);
    fps_kernel<<<B_, 256, 0, stream>>>(xyz, out);           // centroids -> output 0
    knn_kernel<<<NQ, 64, 0, stream>>>(xyz, out, nbr);

    // layer 0 (+fused stats)
    l0_kernel<<<2048, 256, 0, stream>>>(xyz, fea, out, nbr, wt0, yT, MPart);
    stats_fin<<<64, 256, 0, stream>>>(MPart, g0, be0, ab0);

    // layer 1 (in-place, +fused stats)
    l1_kernel<<<2048, 256, 0, stream>>>(yT, wt1, ab0, MPart);
    stats_fin<<<64, 256, 0, stream>>>(MPart, g1, be1, ab1);

    // layer 2: GEMM once (stats + early maxpool), then trivial fin
    l2s_kernel<<<dim3(2048, 2), 256, 0, stream>>>(yT, wt2, ab1, part2s, M);
    stats2_fin<<<128, 256, 0, stream>>>(part2s, g2, be2, ab2);
    fin_kernel<<<8192, 256, 0, stream>>>(M, ab2, out);
}

// Round 10
// 1382.765 us; speedup vs baseline: 1.2735x; 1.2735x over previous
//
#include <hip/hip_runtime.h>
#include <cstdint>
#include <cstddef>

typedef unsigned short ushort_t;
typedef unsigned int uint_t;
typedef unsigned long long u64_t;
typedef float v2f __attribute__((ext_vector_type(2)));

#define B_ 16
#define N_ 4096
#define S_ 1024
#define K_ 32
#define NR 524288    // B*S*K rows
#define NQ 16384     // B*S queries

__device__ __forceinline__ float bf2f(ushort_t u) {
    union { uint_t i; float f; } x; x.i = ((uint_t)u) << 16; return x.f;
}
__device__ __forceinline__ ushort_t f2bf(float f) {
    union { float f; uint_t u; } x; x.f = f;
    uint_t u = x.u;
    uint_t r = (u + 0x7fffu + ((u >> 16) & 1u)) >> 16;   // RNE
    return (ushort_t)r;
}

// ---------------------------------------------------------------------------
// DPP primitives. update_dpp(idt, v, ctrl, 0xF, 0xF, false): invalid lanes
// receive idt (identity).
// ---------------------------------------------------------------------------
template <int CTRL>
__device__ __forceinline__ uint_t dppmov(uint_t v, uint_t idt) {
    return (uint_t)__builtin_amdgcn_update_dpp((int)idt, (int)v, CTRL, 0xF, 0xF, false);
}
template <int CTRL>
__device__ __forceinline__ float dppsum(float v) {
    return v + __uint_as_float(dppmov<CTRL>(__float_as_uint(v), 0u));              // idt = +0.0
}
template <int CTRL>
__device__ __forceinline__ float dppmaxf(float v) {
    return fmaxf(v, __uint_as_float(dppmov<CTRL>(__float_as_uint(v), 0xFF800000u))); // idt = -inf
}

// wave-64 argmax/argmin over unique u64 keys; result in lane 63.
__device__ __forceinline__ void wave_argmax64(uint_t& hi, uint_t& lo) {
#define STEP_MAX(C) { uint_t nh = dppmov<C>(hi, 0u); uint_t nl = dppmov<C>(lo, 0u); \
    u64_t a = ((u64_t)hi << 32) | lo, bb = ((u64_t)nh << 32) | nl; \
    if (bb > a) { hi = nh; lo = nl; } }
    STEP_MAX(0x111) STEP_MAX(0x112) STEP_MAX(0x114) STEP_MAX(0x118)
    STEP_MAX(0x142) STEP_MAX(0x143)
#undef STEP_MAX
}
__device__ __forceinline__ void wave_argmin64(uint_t& hi, uint_t& lo) {
#define STEP_MIN(C) { uint_t nh = dppmov<C>(hi, 0xFFFFFFFFu); uint_t nl = dppmov<C>(lo, 0xFFFFFFFFu); \
    u64_t a = ((u64_t)hi << 32) | lo, bb = ((u64_t)nh << 32) | nl; \
    if (bb < a) { hi = nh; lo = nl; } }
    STEP_MIN(0x111) STEP_MIN(0x112) STEP_MIN(0x114) STEP_MIN(0x118)
    STEP_MIN(0x142) STEP_MIN(0x143)
#undef STEP_MIN
}

// ---------------------------------------------------------------------------
// prep: weights fp32 -> fp32 transposed. wt0[c][64], wt1[c][64], wt2[c][128]
// ---------------------------------------------------------------------------
__global__ __launch_bounds__(256) void prep_kernel(
        const float* __restrict__ W0, const float* __restrict__ W1,
        const float* __restrict__ W2,
        float* __restrict__ wt0, float* __restrict__ wt1, float* __restrict__ wt2) {
    int tid = threadIdx.x;
    for (int i = tid; i < 64 * 67; i += 256) { int o = i / 67, c = i % 67; wt0[c * 64 + o] = W0[i]; }
    for (int i = tid; i < 64 * 64; i += 256) { int o = i >> 6, c = i & 63; wt1[c * 64 + o] = W1[i]; }
    for (int i = tid; i < 128 * 64; i += 256) { int o = i >> 6, c = i & 63; wt2[c * 128 + o] = W2[i]; }
}

// ---------------------------------------------------------------------------
// FPS (R8 structure — fastest measured): one block (4 waves) per batch,
// 16 pts/thread packed as float2 pairs (v_pk_* fp32, identical IEEE).
// In-loop tid0 centroid stores (measured faster than epilogue variants).
// u64-key tree + DPP wave argmax + one barrier combine. Key=(dist_bits,~p).
// ---------------------------------------------------------------------------
__global__ __launch_bounds__(256) void fps_kernel(
        const float* __restrict__ xyz, float* __restrict__ out_sxyz) {
    #pragma clang fp contract(off)
    __shared__ float4 pts[N_];
    __shared__ uint2 cand[2][4];
    int b = blockIdx.x, tid = threadIdx.x;
    int wv = tid >> 6, lane = tid & 63;
    const float* base = xyz + (size_t)b * N_ * 3;

    v2f px[8], py[8], pz[8], dist[8];
    #pragma unroll
    for (int t = 0; t < 16; t++) {
        int p = tid + t * 256;
        float x = base[p * 3 + 0];
        float y = base[p * 3 + 1];
        float z = base[p * 3 + 2];
        px[t >> 1][t & 1] = x; py[t >> 1][t & 1] = y; pz[t >> 1][t & 1] = z;
        pts[p] = make_float4(x, y, z, 0.0f);
        dist[t >> 1][t & 1] = 1e10f;
    }
    __syncthreads();

    int far = 0;
    for (int i = 0; i < S_; i++) {
        float4 c = pts[far];                       // ds_read_b128
        if (tid == 0) {
            int qi = b * S_ + i;
            out_sxyz[qi * 3 + 0] = c.x;
            out_sxyz[qi * 3 + 1] = c.y;
            out_sxyz[qi * 3 + 2] = c.z;
        }
        v2f cx = { c.x, c.x }, cy = { c.y, c.y }, cz = { c.z, c.z };
        #pragma unroll
        for (int j = 0; j < 8; j++) {
            v2f dx = px[j] - cx, dy = py[j] - cy, dz = pz[j] - cz;
            v2f d = (dx * dx + dy * dy) + dz * dz;   // ref sum order
            dist[j] = __builtin_elementwise_min(dist[j], d);
        }
        // local tree argmax over 16 candidates via u64 keys (exact total order)
        uint_t kh[16], kl[16];
        #pragma unroll
        for (int t = 0; t < 16; t++) {
            kh[t] = __float_as_uint(dist[t >> 1][t & 1]);  // dist>=0: uint order = float order
            kl[t] = ~(uint_t)(tid + t * 256);
        }
        #pragma unroll
        for (int st = 8; st >= 1; st >>= 1) {
            #pragma unroll
            for (int t = 0; t < 8; t++) {
                if (t < st) {
                    u64_t a = ((u64_t)kh[t] << 32) | kl[t];
                    u64_t bb = ((u64_t)kh[t + st] << 32) | kl[t + st];
                    if (bb > a) { kh[t] = kh[t + st]; kl[t] = kl[t + st]; }
                }
            }
        }
        uint_t bh = kh[0], bl = kl[0];
        wave_argmax64(bh, bl);                     // lane 63 has wave winner
        int buf = i & 1;
        if (lane == 63) cand[buf][wv] = make_uint2(bh, bl);
        __syncthreads();
        uint2 c0 = cand[buf][0], c1 = cand[buf][1], c2 = cand[buf][2], c3 = cand[buf][3];
        u64_t best = ((u64_t)c0.x << 32) | c0.y;
        u64_t k1 = ((u64_t)c1.x << 32) | c1.y; if (k1 > best) best = k1;
        u64_t k2 = ((u64_t)c2.x << 32) | c2.y; if (k2 > best) best = k2;
        u64_t k3 = ((u64_t)c3.x << 32) | c3.y; if (k3 > best) best = k3;
        far = (int)((~(uint_t)best) & 4095u);
    }
}

// ---------------------------------------------------------------------------
// KNN: one wave per query -> 32 neighbor indices (R7/R8 proven).
// ---------------------------------------------------------------------------
__global__ __launch_bounds__(64) void knn_kernel(
        const float* __restrict__ xyz, const float* __restrict__ qxyz,
        int* __restrict__ nbr) {
    #pragma clang fp contract(off)
    __shared__ uint_t dsm[N_];
    int bs = blockIdx.x;
    int b = bs >> 10;
    int lane = threadIdx.x;
    const float* xb = xyz + (size_t)b * N_ * 3;

    float qx = qxyz[bs * 3 + 0], qy = qxyz[bs * 3 + 1], qz = qxyz[bs * 3 + 2];
    float qq = (qx * qx + qy * qy) + qz * qz;

    uint_t ulv = 0xFFFFFFFFu; int li = 0;
    for (int s = 0; s < 64; s++) {
        int p = s * 64 + lane;
        float x = xb[p * 3 + 0];
        float y = xb[p * 3 + 1];
        float z = xb[p * 3 + 2];
        float pp = (x * x + y * y) + z * z;
        float dt = (qx * x + qy * y) + qz * z;
        float d = (qq + pp) - 2.0f * dt;               // matches ref
        uint_t ub = __float_as_uint(d);
        ub ^= (uint_t)(((int)ub >> 31)) | 0x80000000u; // sortable transform
        dsm[s * 64 + ((lane + s) & 63)] = ub;          // swizzled store
        if (ub < ulv) { ulv = ub; li = p; }
    }
    __syncthreads();

    u64_t mask = 0ull;
    int my_nbr = 0;
    for (int r = 0; r < K_; r++) {
        uint_t hh = ulv, ll = (uint_t)li;
        wave_argmin64(hh, ll);
        int idx = (int)(uint_t)__builtin_amdgcn_readlane((int)ll, 63);
        int glane = idx & 63, srow = idx >> 6;
        if (lane == r) my_nbr = idx;
        if (lane == glane) mask |= 1ull << srow;
        uint_t gml = (uint_t)__builtin_amdgcn_readlane((int)(uint_t)mask, glane);
        uint_t gmh = (uint_t)__builtin_amdgcn_readlane((int)(uint_t)(mask >> 32), glane);
        u64_t gm = ((u64_t)gmh << 32) | gml;
        uint_t cv = ((gm >> lane) & 1ull) ? 0xFFFFFFFFu
                                          : dsm[lane * 64 + ((glane + lane) & 63)];
        uint_t ci = (uint_t)(lane * 64 + glane);
        wave_argmin64(cv, ci);
        uint_t rv = (uint_t)__builtin_amdgcn_readlane((int)cv, 63);
        uint_t ri = (uint_t)__builtin_amdgcn_readlane((int)ci, 63);
        if (lane == glane) { ulv = rv; li = (int)ri; }
    }
    if (lane < K_) nbr[bs * K_ + lane] = my_nbr;
}

// ---------------------------------------------------------------------------
// L0 (R8, no fused stats — avoids acc[] spill): float4 gather + 67x64 FMA.
// ---------------------------------------------------------------------------
__global__ __launch_bounds__(256) void l0_kernel(
        const float* __restrict__ xyz, const float* __restrict__ fea,
        const float* __restrict__ qxyz, const int* __restrict__ nbr,
        const float* __restrict__ wt0, ushort_t* __restrict__ yT) {
    int row = blockIdx.x * 256 + threadIdx.x;
    int bs = row >> 5, b = bs >> 10;
    int p = nbr[row];
    p = (p < 0) ? 0 : (p > N_ - 1 ? N_ - 1 : p);
    float qx = qxyz[bs * 3 + 0], qy = qxyz[bs * 3 + 1], qz = qxyz[bs * 3 + 2];
    const float* xb = xyz + ((size_t)b * N_ + p) * 3;
    float dx = xb[0] - qx, dy = xb[1] - qy, dz = xb[2] - qz;

    float acc[64];
    #pragma unroll
    for (int o = 0; o < 64; o++)
        acc[o] = fmaf(dz, wt0[128 + o], fmaf(dy, wt0[64 + o], dx * wt0[o]));

    const float4* fr = (const float4*)(fea + ((size_t)b * N_ + p) * 64);
    #pragma unroll 2
    for (int i = 0; i < 16; i++) {
        float4 u = fr[i];
        float ua[4] = { u.x, u.y, u.z, u.w };
        #pragma unroll
        for (int j = 0; j < 4; j++) {
            const float* w = wt0 + (3 + i * 4 + j) * 64;
            #pragma unroll
            for (int o = 0; o < 64; o++) acc[o] = fmaf(ua[j], w[o], acc[o]);
        }
    }
    #pragma unroll
    for (int o = 0; o < 64; o++)
        yT[(size_t)o * NR + row] = f2bf(acc[o]);
}

// ---------------------------------------------------------------------------
// BN stats over 64-channel channel-major bf16 buffer (vectorized, R8).
// ---------------------------------------------------------------------------
__global__ __launch_bounds__(256) void stats_pass(
        const ushort_t* __restrict__ y, float* __restrict__ part) {
    int cb = blockIdx.x;
    int c = cb >> 5, ch = cb & 31;
    const uint4* src = (const uint4*)(y + (size_t)c * NR + (size_t)ch * 16384);
    float s = 0.0f, q = 0.0f;
    for (int i = threadIdx.x; i < 2048; i += 256) {
        uint4 u = src[i];
        uint_t ua[4] = { u.x, u.y, u.z, u.w };
        #pragma unroll
        for (int j = 0; j < 4; j++) {
            float v0 = bf2f((ushort_t)(ua[j] & 0xffffu));
            float v1 = bf2f((ushort_t)(ua[j] >> 16));
            s += v0; q = fmaf(v0, v0, q);
            s += v1; q = fmaf(v1, v1, q);
        }
    }
    __shared__ float ls[256], lq[256];
    int tid = threadIdx.x;
    ls[tid] = s; lq[tid] = q;
    __syncthreads();
    for (int off = 128; off >= 1; off >>= 1) {
        if (tid < off) { ls[tid] += ls[tid + off]; lq[tid] += lq[tid + off]; }
        __syncthreads();
    }
    if (tid == 0) { part[cb * 2 + 0] = ls[0]; part[cb * 2 + 1] = lq[0]; }
}

__global__ __launch_bounds__(64) void stats_fin(
        const float* __restrict__ part, const float* __restrict__ g,
        const float* __restrict__ be, float* __restrict__ ab) {
    int o = threadIdx.x;  // C = 64
    double s = 0.0, q = 0.0;
    for (int ch = 0; ch < 32; ch++) {
        s += (double)part[(o * 32 + ch) * 2 + 0];
        q += (double)part[(o * 32 + ch) * 2 + 1];
    }
    double mu = s / (double)NR;
    double var = q / (double)NR - mu * mu;
    if (var < 0.0) var = 0.0;
    double a = (double)g[o] / sqrt(var + 1e-5);
    ab[o]      = (float)a;
    ab[64 + o] = (float)((double)be[o] - mu * a);
}

// ---------------------------------------------------------------------------
// L1 (R8): in-place on yT. Each thread owns one row.
// ---------------------------------------------------------------------------
__global__ __launch_bounds__(256) void l1_kernel(
        ushort_t* yT, const float* __restrict__ wt1, const float* __restrict__ ab) {
    int row = blockIdx.x * 256 + threadIdx.x;
    float xv[64];
    #pragma unroll
    for (int c = 0; c < 64; c++)
        xv[c] = fmaxf(fmaf(bf2f(yT[(size_t)c * NR + row]), ab[c], ab[64 + c]), 0.0f);
    float acc[64];
    #pragma unroll
    for (int o = 0; o < 64; o++) acc[o] = 0.0f;
    #pragma unroll 4
    for (int c = 0; c < 64; c++) {
        const float* w = wt1 + c * 64;
        #pragma unroll
        for (int o = 0; o < 64; o++) acc[o] = fmaf(xv[c], w[o], acc[o]);
    }
    #pragma unroll
    for (int o = 0; o < 64; o++)
        yT[(size_t)o * NR + row] = f2bf(acc[o]);
}

// ---------------------------------------------------------------------------
// L2 stats + EARLY MAXPOOL (R8 structure, R9-validated DPP reductions):
// recompute y2 rows, per-channel sums (s,q) -> block partials, per-query
// max M (BN2 scale a>0: maxpool commutes with BN+ReLU).
// part2s: [2][128][2048]. M: [16384][128].
// ---------------------------------------------------------------------------
__global__ __launch_bounds__(256) void l2s_kernel(
        const ushort_t* __restrict__ yT, const float* __restrict__ wt2,
        const float* __restrict__ ab1, float* __restrict__ part2s,
        float* __restrict__ M) {
    int bx = blockIdx.x, half = blockIdx.y;
    int tid = threadIdx.x;
    int row = bx * 256 + tid;
    int lane = tid & 63, wv = tid >> 6;
    float xv[64];
    #pragma unroll
    for (int c = 0; c < 64; c++)
        xv[c] = fmaxf(fmaf(bf2f(yT[(size_t)c * NR + row]), ab1[c], ab1[64 + c]), 0.0f);
    float acc[64];
    #pragma unroll
    for (int o = 0; o < 64; o++) acc[o] = 0.0f;
    const float* w = wt2 + half * 64;
    #pragma unroll 4
    for (int c = 0; c < 64; c++) {
        const float* wr = w + c * 128;
        #pragma unroll
        for (int o = 0; o < 64; o++) acc[o] = fmaf(xv[c], wr[o], acc[o]);
    }
    __shared__ float Msm[4][2][64];
    __shared__ float Ssm[4][64], Qsm[4][64];
    #pragma unroll 4
    for (int o = 0; o < 64; o++) {
        float v = acc[o];
        float m = v;
        m = dppmaxf<0x111>(m); m = dppmaxf<0x112>(m); m = dppmaxf<0x114>(m);
        m = dppmaxf<0x118>(m); m = dppmaxf<0x142>(m);   // lane31: max(0..31), lane63: max(32..63)
        float s = v, q = v * v;
        s = dppsum<0x111>(s); s = dppsum<0x112>(s); s = dppsum<0x114>(s);
        s = dppsum<0x118>(s); s = dppsum<0x142>(s); s = dppsum<0x143>(s);
        q = dppsum<0x111>(q); q = dppsum<0x112>(q); q = dppsum<0x114>(q);
        q = dppsum<0x118>(q); q = dppsum<0x142>(q); q = dppsum<0x143>(q);
        if (lane == 31) Msm[wv][0][o] = m;
        if (lane == 63) { Msm[wv][1][o] = m; Ssm[wv][o] = s; Qsm[wv][o] = q; }
    }
    __syncthreads();
    // M epilogue: 512 entries, coalesced
    #pragma unroll
    for (int r = 0; r < 2; r++) {
        int e = tid + r * 256;
        int ewv = e >> 7, eq = (e >> 6) & 1, eo = e & 63;
        M[(size_t)(bx * 8 + ewv * 2 + eq) * 128 + half * 64 + eo] = Msm[ewv][eq][eo];
    }
    if (tid < 64) {
        float s = Ssm[0][tid] + Ssm[1][tid] + Ssm[2][tid] + Ssm[3][tid];
        part2s[(size_t)(half * 64 + tid) * 2048 + bx] = s;
    } else if (tid < 128) {
        int ch = tid - 64;
        float q = Qsm[0][ch] + Qsm[1][ch] + Qsm[2][ch] + Qsm[3][ch];
        part2s[(size_t)128 * 2048 + (size_t)(half * 64 + ch) * 2048 + bx] = q;
    }
}

__global__ __launch_bounds__(256) void stats2_fin(
        const float* __restrict__ part2s, const float* __restrict__ g,
        const float* __restrict__ be, float* __restrict__ ab2) {
    int og = blockIdx.x;  // 0..127
    float s = 0.0f, q = 0.0f;
    for (int col = threadIdx.x; col < 2048; col += 256) {
        s += part2s[(size_t)og * 2048 + col];
        q += part2s[(size_t)128 * 2048 + (size_t)og * 2048 + col];
    }
    __shared__ float ls[256], lq[256];
    int tid = threadIdx.x;
    ls[tid] = s; lq[tid] = q;
    __syncthreads();
    for (int off = 128; off >= 1; off >>= 1) {
        if (tid < off) { ls[tid] += ls[tid + off]; lq[tid] += lq[tid + off]; }
        __syncthreads();
    }
    if (tid == 0) {
        double mu = (double)ls[0] / (double)NR;
        double var = (double)lq[0] / (double)NR - mu * mu;
        if (var < 0.0) var = 0.0;
        double a = (double)g[og] / sqrt(var + 1e-5);
        ab2[og]       = (float)a;
        ab2[128 + og] = (float)((double)be[og] - mu * a);
    }
}

// ---------------------------------------------------------------------------
// fin: out = relu(a*M + c)  (valid: a = g/sqrt(var) > 0).
// ---------------------------------------------------------------------------
__global__ __launch_bounds__(256) void fin_kernel(
        const float* __restrict__ M, const float* __restrict__ ab2,
        float* __restrict__ out) {
    int idx = blockIdx.x * 256 + threadIdx.x;   // 0 .. 2097151
    int og = idx & 127;
    out[49152 + idx] = fmaxf(fmaf(M[idx], ab2[og], ab2[128 + og]), 0.0f);
}

// ---------------------------------------------------------------------------
extern "C" void kernel_launch(void* const* d_in, const int* in_sizes, int n_in,
                              void* d_out, int out_size, void* d_ws, size_t ws_size,
                              hipStream_t stream) {
    const float* xyz = (const float*)d_in[0];
    const float* fea = (const float*)d_in[1];
    const float* W0  = (const float*)d_in[2];
    const float* g0  = (const float*)d_in[4];
    const float* be0 = (const float*)d_in[5];
    const float* W1  = (const float*)d_in[6];
    const float* g1  = (const float*)d_in[8];
    const float* be1 = (const float*)d_in[9];
    const float* W2  = (const float*)d_in[10];
    const float* g2  = (const float*)d_in[12];
    const float* be2 = (const float*)d_in[13];
    float* out = (float*)d_out;

    char* w = (char*)d_ws;
    // footprint ~74.1 MB (proven layout)
    ushort_t* yT    = (ushort_t*)(w);                      // 67,108,864
    int*      nbr   = (int*)     (w + 67108864);           //  2,097,152 (dead after l0)
    float*    part2s= (float*)   (w + 67108864);           //  2,097,152 (l2s partials, aliases nbr)
    float*    part  = (float*)   (w + 69206016);           //     16,384
    float*    M     = (float*)   (w + 69222400);           //  8,388,608
    float*    ab0   = (float*)   (w + 77611008);           //        512
    float*    ab1   = (float*)   (w + 77611520);           //        512
    float*    ab2   = (float*)   (w + 77612032);           //      1,024
    float*    wt0   = (float*)   (w + 77613056);           //     17,152
    float*    wt1   = (float*)   (w + 77630208);           //     16,384
    float*    wt2   = (float*)   (w + 77646592);           //     32,768

    prep_kernel<<<1, 256, 0, stream>>>(W0, W1, W2, wt0, wt1, wt2);
    fps_kernel<<<B_, 256, 0, stream>>>(xyz, out);           // centroids -> output 0
    knn_kernel<<<NQ, 64, 0, stream>>>(xyz, out, nbr);

    // layer 0
    l0_kernel<<<2048, 256, 0, stream>>>(xyz, fea, out, nbr, wt0, yT);
    stats_pass<<<64 * 32, 256, 0, stream>>>(yT, part);
    stats_fin<<<1, 64, 0, stream>>>(part, g0, be0, ab0);

    // layer 1 (in-place)
    l1_kernel<<<2048, 256, 0, stream>>>(yT, wt1, ab0);
    stats_pass<<<64 * 32, 256, 0, stream>>>(yT, part);
    stats_fin<<<1, 64, 0, stream>>>(part, g1, be1, ab1);

    // layer 2: GEMM once (stats + early maxpool), then trivial fin
    l2s_kernel<<<dim3(2048, 2), 256, 0, stream>>>(yT, wt2, ab1, part2s, M);
    stats2_fin<<<128, 256, 0, stream>>>(part2s, g2, be2, ab2);
    fin_kernel<<<8192, 256, 0, stream>>>(M, ab2, out);
}